// Round 7
// baseline (365.432 us; speedup 1.0000x reference)
//
#include <hip/hip_runtime.h>
#include <stdint.h>

typedef unsigned short u16;
typedef __attribute__((ext_vector_type(8))) short short8;
typedef __attribute__((ext_vector_type(4))) short short4v;
typedef __attribute__((ext_vector_type(4))) float f32x4;

#define LOG2E 1.44269504088896340736f

#define Bb 8
#define NSEQ 1024
#define DIMC 768
#define NH 12
#define DH 64
#define INNER 768
#define MTOT (Bb*NSEQ)      /* 8192 */
#define QKVN (3*INNER)      /* 2304 */
#define HEADS_TOT (Bb*NH)   /* 96 */
#define QKV_PART ((size_t)Bb*NH*NSEQ*DH)

static __device__ inline u16 f2bf(float f) {
    uint32_t u = __builtin_bit_cast(uint32_t, f);
    uint32_t r = (u + 0x7fffu + ((u >> 16) & 1u)) >> 16;
    return (u16)r;
}

static __device__ __forceinline__ uint32_t pkbf(float f0, float f1) {
    uint32_t u0 = __builtin_bit_cast(uint32_t, f0) + 0x8000u;
    uint32_t u1 = __builtin_bit_cast(uint32_t, f1) + 0x8000u;
    return __builtin_amdgcn_perm(u1, u0, 0x07060302u);
}

#if __has_builtin(__builtin_amdgcn_mfma_f32_16x16x16bf16_1k)
static __device__ __forceinline__ f32x4 mfma16(short4v a, short4v b, f32x4 c) {
    return __builtin_amdgcn_mfma_f32_16x16x16bf16_1k(a, b, c, 0, 0, 0);
}
#else
static __device__ __forceinline__ f32x4 mfma16(short4v a, short4v b, f32x4 c) {
    asm volatile("v_mfma_f32_16x16x16_bf16 %0, %1, %2, %0\n\ts_nop 7\n\ts_nop 7"
                 : "+v"(c) : "v"(a), "v"(b));
    return c;
}
#endif

// ---------------- fused fp32 -> bf16 conversion (single dispatch) ----------------
#define NX8  786432
#define NWQ8 221184
#define NWP8 73728
#define NCVT (NX8 + NWQ8 + NWP8)
__global__ __launch_bounds__(256) void cvt_all(const float* __restrict__ x,
                                               const float* __restrict__ wq,
                                               const float* __restrict__ wp,
                                               u16* __restrict__ xb,
                                               u16* __restrict__ wqb,
                                               u16* __restrict__ wpb) {
    int i = blockIdx.x * 256 + threadIdx.x;
    const float* s; u16* d; int j;
    if (i < NX8) { s = x; d = xb; j = i; }
    else if (i < NX8 + NWQ8) { s = wq; d = wqb; j = i - NX8; }
    else { s = wp; d = wpb; j = i - NX8 - NWQ8; }
    const float4* s4 = (const float4*)s;
    float4 a = s4[2 * j], b = s4[2 * j + 1];
    float v[8] = {a.x, a.y, a.z, a.w, b.x, b.y, b.z, b.w};
    u16 o[8];
#pragma unroll
    for (int t = 0; t < 8; t++) o[t] = f2bf(v[t]);
    ((uint4*)d)[j] = *(const uint4*)o;
}

// ============ shared GEMM core: 256 thr, 128x128 tile, BK=64 ============
// Staging: global->VGPR (prefetched one tile ahead) -> ds_write_b128.
// LDS rows 64 bf16 = 8 chunks of 16B; chunk (r,c) at slot r*64 + ((c+r)&7)*8.
// Loop: barrier / ds_write tile i / issue global loads i+1 / barrier / compute.
// Global latency rides through the compute phase; barriers drain LDS only.
#define BK 64

template <int MODE>  // 0: qkv scatter epilogue, 1: fp32 row-major epilogue
__global__ __launch_bounds__(256) void gemm_bt(const u16* __restrict__ A,
                                               const u16* __restrict__ Bm,
                                               void* __restrict__ Cout,
                                               int K, int N) {
    __shared__ u16 As[128 * BK];   // 16 KB
    __shared__ u16 Bs[128 * BK];   // 16 KB
    const int tid = threadIdx.x;
    const int w = tid >> 6, lane = tid & 63, quad = lane >> 4, l16 = lane & 15;
    const int wr = w >> 1, wc = w & 1;
    const int m0 = blockIdx.y * 128;
    const int n0 = blockIdx.x * 128;

    // staging: thread handles rows j*32 + (tid>>3), chunk sc = tid&7 (4 chunks each)
    const int sr = tid >> 3, sc = tid & 7;
    const u16* agp[4]; const u16* bgp[4]; int lsl[4];
#pragma unroll
    for (int j = 0; j < 4; j++) {
        int r = j * 32 + sr;
        agp[j] = A + (size_t)(m0 + r) * K + sc * 8;
        bgp[j] = Bm + (size_t)(n0 + r) * K + sc * 8;
        lsl[j] = r * BK + ((sc + r) & 7) * 8;
    }

    int abase[4], bbase[4], sw[2];
#pragma unroll
    for (int t = 0; t < 4; t++) {
        abase[t] = (wr * 64 + t * 16 + l16) * BK;
        bbase[t] = (wc * 64 + t * 16 + l16) * BK;
    }
#pragma unroll
    for (int kc = 0; kc < 2; kc++) sw[kc] = ((quad + 4 * kc + l16) & 7) * 8;

    // prefetch tile 0 into VGPRs
    uint4 apre[4], bpre[4];
#pragma unroll
    for (int j = 0; j < 4; j++) {
        apre[j] = *(const uint4*)(agp[j]);
        bpre[j] = *(const uint4*)(bgp[j]);
    }

    f32x4 acc[4][4] = {};
    const int NIT = K / BK;   // 12
    for (int it = 0; it < NIT; ++it) {
        __syncthreads();   // prev iter's ds_reads complete (WAR on LDS)
#pragma unroll
        for (int j = 0; j < 4; j++) {
            *(uint4*)(As + lsl[j]) = apre[j];
            *(uint4*)(Bs + lsl[j]) = bpre[j];
        }
        // issue next tile's global loads (wave-private VGPRs; in flight thru compute)
        int ktn = (it + 1 < NIT) ? (it + 1) * BK : 0;
#pragma unroll
        for (int j = 0; j < 4; j++) {
            apre[j] = *(const uint4*)(agp[j] + ktn);
            bpre[j] = *(const uint4*)(bgp[j] + ktn);
        }
        __syncthreads();   // drains lgkmcnt (ds_write) only — cheap
#pragma unroll
        for (int kc = 0; kc < 2; kc++) {
            short8 af[4], bf[4];
#pragma unroll
            for (int t = 0; t < 4; t++) af[t] = *(const short8*)(As + abase[t] + sw[kc]);
#pragma unroll
            for (int t = 0; t < 4; t++) bf[t] = *(const short8*)(Bs + bbase[t] + sw[kc]);
#pragma unroll
            for (int mt = 0; mt < 4; mt++)
#pragma unroll
                for (int nt = 0; nt < 4; nt++)
                    acc[mt][nt] = __builtin_amdgcn_mfma_f32_16x16x32_bf16(af[mt], bf[nt],
                                                                          acc[mt][nt], 0, 0, 0);
        }
    }

    if (MODE == 0) {
        u16* qkv = (u16*)Cout;
#pragma unroll
        for (int nt = 0; nt < 4; nt++) {
            int o = n0 + wc * 64 + nt * 16 + l16;
            int which = o / 768;
            int rem = o - which * 768;
            int h = rem >> 6, d = rem & 63;
            if (which == 2) {
                u16* vt = qkv + 2 * QKV_PART;
#pragma unroll
                for (int mt = 0; mt < 4; mt++) {
                    int m = m0 + wr * 64 + mt * 16 + quad * 4;
                    int bb = m >> 10, ns = m & 1023;
                    alignas(8) u16 pk[4];
#pragma unroll
                    for (int r = 0; r < 4; r++) pk[r] = f2bf(acc[mt][nt][r]);
                    *(uint2*)(vt + ((size_t)(bb * NH + h) * DH + d) * NSEQ + ns) =
                        *(const uint2*)pk;
                }
            } else {
                float sc2 = (which == 0) ? (0.125f * LOG2E) : 1.0f;
#pragma unroll
                for (int mt = 0; mt < 4; mt++)
#pragma unroll
                    for (int r = 0; r < 4; r++) {
                        int m = m0 + wr * 64 + mt * 16 + quad * 4 + r;
                        int bb = m >> 10, ns = m & 1023;
                        size_t idx = (size_t)which * QKV_PART +
                                     (((size_t)(bb * NH + h) * NSEQ + ns) << 6) + d;
                        qkv[idx] = f2bf(acc[mt][nt][r] * sc2);
                    }
            }
        }
    } else {
        float* Co = (float*)Cout;
#pragma unroll
        for (int mt = 0; mt < 4; mt++)
#pragma unroll
            for (int nt = 0; nt < 4; nt++) {
                int o = n0 + wc * 64 + nt * 16 + l16;
#pragma unroll
                for (int r = 0; r < 4; r++) {
                    int m = m0 + wr * 64 + mt * 16 + quad * 4 + r;
                    Co[(size_t)m * N + o] = acc[mt][nt][r];
                }
            }
    }
}

// ---------------- Flash attention v7: VGPR-prefetch pipeline, co-XCD heads --------
// grid (96 bh, 8 qt). 64-key tiles; K(64x64) and V^T(64x64) staged via VGPR
// prefetch + ds_write_b128, rotation swizzle slot = r*64 + ((c+r)&7)*8.
__global__ __launch_bounds__(256) void attn_kernel(const u16* __restrict__ qkv,
                                                   u16* __restrict__ attn) {
    __shared__ u16 Ks[64 * 64];   // 8 KB
    __shared__ u16 Vs[64 * 64];   // 8 KB

    const int tid = threadIdx.x;
    const int w = tid >> 6, lane = tid & 63, quad = lane >> 4, l16 = lane & 15;
    const int bh = blockIdx.x, qt = blockIdx.y;
    const size_t headoff = (size_t)bh * NSEQ * DH;
    const u16* Qp = qkv + headoff;
    const u16* Kp = qkv + QKV_PART + headoff;
    const u16* Vtp = qkv + 2 * QKV_PART + headoff;
    const int q0 = qt * 128 + w * 32;

    // staging: thread handles rows j*32 + (tid>>3), chunk sc = tid&7 (2 each)
    const int sr = tid >> 3, sc = tid & 7;
    const u16* kg[2]; const u16* vg[2]; int lsl[2];
#pragma unroll
    for (int j = 0; j < 2; j++) {
        int r = j * 32 + sr;
        kg[j] = Kp + (size_t)r * DH + sc * 8;      // K rows: key pos
        vg[j] = Vtp + (size_t)r * NSEQ + sc * 8;   // V^T rows: d
        lsl[j] = r * 64 + ((sc + r) & 7) * 8;
    }

    const int sw0 = ((quad + l16) & 7) * 8;
    const int sw1 = ((quad + 4 + l16) & 7) * 8;

    short8 qf[2][2];
#pragma unroll
    for (int mf = 0; mf < 2; mf++) {
        qf[mf][0] = *(const short8*)(Qp + (size_t)(q0 + mf * 16 + l16) * DH + quad * 8);
        qf[mf][1] = *(const short8*)(Qp + (size_t)(q0 + mf * 16 + l16) * DH + 32 + quad * 8);
    }

    // prefetch tile 0
    uint4 kpre[2], vpre[2];
#pragma unroll
    for (int j = 0; j < 2; j++) {
        kpre[j] = *(const uint4*)(kg[j]);
        vpre[j] = *(const uint4*)(vg[j]);
    }

    f32x4 oacc[2][4] = {};
    float lsum[2] = {0.f, 0.f};

    const int NIT = NSEQ / 64;   // 16
    for (int it = 0; it < NIT; ++it) {
        __syncthreads();
#pragma unroll
        for (int j = 0; j < 2; j++) {
            *(uint4*)(Ks + lsl[j]) = kpre[j];
            *(uint4*)(Vs + lsl[j]) = vpre[j];
        }
        int ktn = (it + 1 < NIT) ? (it + 1) * 64 : 0;
#pragma unroll
        for (int j = 0; j < 2; j++) {
            kpre[j] = *(const uint4*)(kg[j] + (size_t)ktn * DH);
            vpre[j] = *(const uint4*)(vg[j] + ktn);
        }
        __syncthreads();

        short8 kf[4][2];
#pragma unroll
        for (int nt = 0; nt < 4; nt++) {
            const u16* kr = Ks + (nt * 16 + l16) * 64;
            kf[nt][0] = *(const short8*)(kr + sw0);
            kf[nt][1] = *(const short8*)(kr + sw1);
        }
        short4v vf[4][4];
#pragma unroll
        for (int nt2 = 0; nt2 < 4; nt2++) {
            int row = nt2 * 16 + l16;
#pragma unroll
            for (int c = 0; c < 4; c++) {
                int off = row * 64 + (((c * 2 + (quad >> 1) + row) & 7) << 3) + (quad & 1) * 4;
                vf[nt2][c] = *(const short4v*)(Vs + off);
            }
        }

#pragma unroll
        for (int mf = 0; mf < 2; mf++) {
            f32x4 st[4];
#pragma unroll
            for (int nt = 0; nt < 4; nt++) {
                f32x4 z = {};
                z = __builtin_amdgcn_mfma_f32_16x16x32_bf16(kf[nt][0], qf[mf][0], z, 0, 0, 0);
                z = __builtin_amdgcn_mfma_f32_16x16x32_bf16(kf[nt][1], qf[mf][1], z, 0, 0, 0);
                st[nt] = z;
            }
            short4v pf[4];
#pragma unroll
            for (int c = 0; c < 4; c++) {
                float p0 = __builtin_amdgcn_exp2f(st[c][0]);
                float p1 = __builtin_amdgcn_exp2f(st[c][1]);
                float p2 = __builtin_amdgcn_exp2f(st[c][2]);
                float p3 = __builtin_amdgcn_exp2f(st[c][3]);
                lsum[mf] += (p0 + p1) + (p2 + p3);
                uint2 u = {pkbf(p0, p1), pkbf(p2, p3)};
                pf[c] = __builtin_bit_cast(short4v, u);
            }
#pragma unroll
            for (int nt2 = 0; nt2 < 4; nt2++)
#pragma unroll
                for (int c = 0; c < 4; c++)
                    oacc[mf][nt2] = mfma16(vf[nt2][c], pf[c], oacc[mf][nt2]);
        }
    }

#pragma unroll
    for (int mf = 0; mf < 2; mf++) {
        float v = lsum[mf];
        v += __shfl_xor(v, 16);
        v += __shfl_xor(v, 32);
        lsum[mf] = 1.0f / v;
    }

    const int b = bh / NH, h = bh - (bh / NH) * NH;
#pragma unroll
    for (int mf = 0; mf < 2; mf++) {
        int q = q0 + mf * 16 + l16;
        float inv = lsum[mf];
#pragma unroll
        for (int nt2 = 0; nt2 < 4; nt2++) {
            uint2 u = {pkbf(oacc[mf][nt2][0] * inv, oacc[mf][nt2][1] * inv),
                       pkbf(oacc[mf][nt2][2] * inv, oacc[mf][nt2][3] * inv)};
            int d = nt2 * 16 + quad * 4;
            *(uint2*)(attn + ((size_t)(b * NSEQ + q)) * INNER + h * DH + d) = u;
        }
    }
}

extern "C" void kernel_launch(void* const* d_in, const int* in_sizes, int n_in,
                              void* d_out, int out_size, void* d_ws, size_t ws_size,
                              hipStream_t stream) {
    const float* x = (const float*)d_in[0];
    const float* w_qkv = (const float*)d_in[1];
    const float* w_proj = (const float*)d_in[2];
    float* out = (float*)d_out;

    u16* xb = (u16*)d_ws;
    u16* wqkvb = xb + 6291456;
    u16* wprojb = wqkvb + 1769472;
    u16* qkvb = wprojb + 589824;
    u16* attnb = qkvb + 18874368;

    cvt_all<<<NCVT / 256, 256, 0, stream>>>(x, w_qkv, w_proj, xb, wqkvb, wprojb);

    dim3 g1(QKVN / 128, MTOT / 128);   // (18, 64) — natural order (no XCD swizzle)
    gemm_bt<0><<<g1, 256, 0, stream>>>(xb, wqkvb, qkvb, DIMC, QKVN);

    dim3 g2(HEADS_TOT, NSEQ / 128);    // (96, 8) — same-head blocks co-XCD
    attn_kernel<<<g2, 256, 0, stream>>>(qkvb, attnb);

    dim3 g3(INNER / 128, MTOT / 128);  // (6, 64)
    gemm_bt<1><<<g3, 256, 0, stream>>>(attnb, wprojb, out, INNER, DIMC);
}

// Round 8
// 203.068 us; speedup vs baseline: 1.7996x; 1.7996x over previous
//
#include <hip/hip_runtime.h>
#include <stdint.h>

typedef unsigned short u16;
typedef __attribute__((ext_vector_type(8))) short short8;
typedef __attribute__((ext_vector_type(4))) short short4v;
typedef __attribute__((ext_vector_type(4))) float f32x4;

#define LOG2E 1.44269504088896340736f

#define Bb 8
#define NSEQ 1024
#define DIMC 768
#define NH 12
#define DH 64
#define INNER 768
#define MTOT (Bb*NSEQ)      /* 8192 */
#define QKVN (3*INNER)      /* 2304 */
#define HEADS_TOT (Bb*NH)   /* 96 */
#define QKV_PART ((size_t)Bb*NH*NSEQ*DH)

static __device__ inline u16 f2bf(float f) {
    uint32_t u = __builtin_bit_cast(uint32_t, f);
    uint32_t r = (u + 0x7fffu + ((u >> 16) & 1u)) >> 16;
    return (u16)r;
}

// pack two f32 -> bf16 pair (round-half-up) in 3 VALU ops via v_perm
static __device__ __forceinline__ uint32_t pkbf(float f0, float f1) {
    uint32_t u0 = __builtin_bit_cast(uint32_t, f0) + 0x8000u;
    uint32_t u1 = __builtin_bit_cast(uint32_t, f1) + 0x8000u;
    return __builtin_amdgcn_perm(u1, u0, 0x07060302u);
}

// 16x16x16 bf16 MFMA: B-operand k-packing matches 16x16 MFMA C-layout
#if __has_builtin(__builtin_amdgcn_mfma_f32_16x16x16bf16_1k)
static __device__ __forceinline__ f32x4 mfma16(short4v a, short4v b, f32x4 c) {
    return __builtin_amdgcn_mfma_f32_16x16x16bf16_1k(a, b, c, 0, 0, 0);
}
#else
static __device__ __forceinline__ f32x4 mfma16(short4v a, short4v b, f32x4 c) {
    asm volatile("v_mfma_f32_16x16x16_bf16 %0, %1, %2, %0\n\ts_nop 7\n\ts_nop 7"
                 : "+v"(c) : "v"(a), "v"(b));
    return c;
}
#endif

// ---- async global->LDS, 16B per lane; keeps staged data OUT of the VGPR file
// (round-7 VGPR staging spilled: WRITE_SIZE 42->266 MB. Do not regress this.) ----
typedef __attribute__((address_space(1))) const void gas_void;
typedef __attribute__((address_space(3))) void las_void;
static __device__ __forceinline__ void async16(u16* lds, const u16* g) {
    __builtin_amdgcn_global_load_lds((gas_void*)(uintptr_t)g,
                                     (las_void*)(uintptr_t)lds, 16, 0, 0);
}

// ---------------- fused fp32 -> bf16 conversion (single dispatch) ----------------
#define NX8  786432
#define NWQ8 221184
#define NWP8 73728
#define NCVT (NX8 + NWQ8 + NWP8)
__global__ __launch_bounds__(256) void cvt_all(const float* __restrict__ x,
                                               const float* __restrict__ wq,
                                               const float* __restrict__ wp,
                                               u16* __restrict__ xb,
                                               u16* __restrict__ wqb,
                                               u16* __restrict__ wpb) {
    int i = blockIdx.x * 256 + threadIdx.x;
    const float* s; u16* d; int j;
    if (i < NX8) { s = x; d = xb; j = i; }
    else if (i < NX8 + NWQ8) { s = wq; d = wqb; j = i - NX8; }
    else { s = wp; d = wpb; j = i - NX8 - NWQ8; }
    const float4* s4 = (const float4*)s;
    float4 a = s4[2 * j], b = s4[2 * j + 1];
    float v[8] = {a.x, a.y, a.z, a.w, b.x, b.y, b.z, b.w};
    u16 o[8];
#pragma unroll
    for (int t = 0; t < 8; t++) o[t] = f2bf(v[t]);
    ((uint4*)d)[j] = *(const uint4*)o;
}

// ---------------- QKV GEMM: 512 thr, 128x256, BK=32 (round-4 proven: 59.4 us) ------
#define BK 32
__global__ __launch_bounds__(512, 4) void gemm_qkv(const u16* __restrict__ A,
                                                   const u16* __restrict__ Bm,
                                                   u16* __restrict__ qkv) {
    __shared__ u16 As[128 * BK];   // 8 KB
    __shared__ u16 Bs[256 * BK];   // 16 KB
    const int tid = threadIdx.x;
    const int w = tid >> 6, lane = tid & 63, quad = lane >> 4, l16 = lane & 15;
    const int wr = w >> 2, wc = w & 3;           // 2 x 4 wave grid, 64x64 each
    const int m0 = blockIdx.y * 128;
    const int n0 = blockIdx.x * 256;
    const int K = DIMC;

    const int rl = lane >> 2, cc = lane & 3;
    const int ra = w * 16 + rl;
    const u16* agp = A + (size_t)(m0 + ra) * K + ((cc - ((ra >> 1) & 3)) & 3) * 8;
    u16* alp = As + (w * 16) * BK;
    const u16* bgp[2]; u16* blp[2];
#pragma unroll
    for (int j = 0; j < 2; j++) {
        int rb = w * 32 + j * 16 + rl;
        bgp[j] = Bm + (size_t)(n0 + rb) * K + ((cc - ((rb >> 1) & 3)) & 3) * 8;
        blp[j] = Bs + (w * 32 + j * 16) * BK;
    }

    const int swz = ((quad + ((l16 >> 1) & 3)) & 3) * 8;
    int aoff[4], boff[4];
#pragma unroll
    for (int t = 0; t < 4; t++) {
        aoff[t] = (wr * 64 + t * 16 + l16) * BK + swz;
        boff[t] = (wc * 64 + t * 16 + l16) * BK + swz;
    }

    f32x4 acc[4][4] = {};
    for (int kt = 0; kt < K; kt += BK) {
        __syncthreads();
        async16(alp, agp + kt);
        async16(blp[0], bgp[0] + kt);
        async16(blp[1], bgp[1] + kt);
        __syncthreads();
        short8 af[4], bf[4];
#pragma unroll
        for (int t = 0; t < 4; t++) af[t] = *(const short8*)(As + aoff[t]);
#pragma unroll
        for (int t = 0; t < 4; t++) bf[t] = *(const short8*)(Bs + boff[t]);
#pragma unroll
        for (int mt = 0; mt < 4; mt++)
#pragma unroll
            for (int nt = 0; nt < 4; nt++)
                acc[mt][nt] = __builtin_amdgcn_mfma_f32_16x16x32_bf16(af[mt], bf[nt],
                                                                      acc[mt][nt], 0, 0, 0);
    }

#pragma unroll
    for (int nt = 0; nt < 4; nt++) {
        int o = n0 + wc * 64 + nt * 16 + l16;
        int which = o / 768;
        int rem = o - which * 768;
        int h = rem >> 6, d = rem & 63;
        if (which == 2) {
            u16* vt = qkv + 2 * QKV_PART;
#pragma unroll
            for (int mt = 0; mt < 4; mt++) {
                int m = m0 + wr * 64 + mt * 16 + quad * 4;
                int bb = m >> 10, ns = m & 1023;
                alignas(8) u16 pk[4];
#pragma unroll
                for (int r = 0; r < 4; r++) pk[r] = f2bf(acc[mt][nt][r]);
                *(uint2*)(vt + ((size_t)(bb * NH + h) * DH + d) * NSEQ + ns) =
                    *(const uint2*)pk;
            }
        } else {
            float sc = (which == 0) ? (0.125f * LOG2E) : 1.0f;
#pragma unroll
            for (int mt = 0; mt < 4; mt++)
#pragma unroll
                for (int r = 0; r < 4; r++) {
                    int m = m0 + wr * 64 + mt * 16 + quad * 4 + r;
                    int bb = m >> 10, ns = m & 1023;
                    size_t idx = (size_t)which * QKV_PART +
                                 (((size_t)(bb * NH + h) * NSEQ + ns) << 6) + d;
                    qkv[idx] = f2bf(acc[mt][nt][r] * sc);
                }
        }
    }
}

// ---------------- proj GEMM: 256 thr, 128x128, BK=32 (round-3 proven) --------------
__global__ __launch_bounds__(256) void gemm_proj(const u16* __restrict__ A,
                                                 const u16* __restrict__ Bm,
                                                 float* __restrict__ Co) {
    __shared__ u16 As[128 * BK];
    __shared__ u16 Bs[128 * BK];
    const int tid = threadIdx.x;
    const int w = tid >> 6, lane = tid & 63, quad = lane >> 4, l16 = lane & 15;
    const int wr = w >> 1, wc = w & 1;
    const int m0 = blockIdx.y * 128;
    const int n0 = blockIdx.x * 128;
    const int K = INNER, N = DIMC;

    const int rl = lane >> 2, cc = lane & 3;
    const u16* ag[2]; const u16* bg[2]; u16* al[2]; u16* bl[2];
#pragma unroll
    for (int j = 0; j < 2; j++) {
        int r = w * 32 + j * 16 + rl;
        int c = ((cc - ((r >> 1) & 3)) & 3) * 8;
        ag[j] = A + (size_t)(m0 + r) * K + c;
        bg[j] = Bm + (size_t)(n0 + r) * K + c;
        al[j] = As + (w * 32 + j * 16) * BK;
        bl[j] = Bs + (w * 32 + j * 16) * BK;
    }
    const int swz = ((quad + ((l16 >> 1) & 3)) & 3) * 8;
    int aoff[4], boff[4];
#pragma unroll
    for (int t = 0; t < 4; t++) {
        aoff[t] = (wr * 64 + t * 16 + l16) * BK + swz;
        boff[t] = (wc * 64 + t * 16 + l16) * BK + swz;
    }

    f32x4 acc[4][4] = {};
    for (int kt = 0; kt < K; kt += BK) {
        __syncthreads();
#pragma unroll
        for (int j = 0; j < 2; j++) {
            async16(al[j], ag[j] + kt);
            async16(bl[j], bg[j] + kt);
        }
        __syncthreads();
        short8 af[4], bf[4];
#pragma unroll
        for (int t = 0; t < 4; t++) af[t] = *(const short8*)(As + aoff[t]);
#pragma unroll
        for (int t = 0; t < 4; t++) bf[t] = *(const short8*)(Bs + boff[t]);
#pragma unroll
        for (int mt = 0; mt < 4; mt++)
#pragma unroll
            for (int nt = 0; nt < 4; nt++)
                acc[mt][nt] = __builtin_amdgcn_mfma_f32_16x16x32_bf16(af[mt], bf[nt],
                                                                      acc[mt][nt], 0, 0, 0);
    }
#pragma unroll
    for (int mt = 0; mt < 4; mt++)
#pragma unroll
        for (int nt = 0; nt < 4; nt++) {
            int o = n0 + wc * 64 + nt * 16 + l16;
#pragma unroll
            for (int r = 0; r < 4; r++) {
                int m = m0 + wr * 64 + mt * 16 + quad * 4 + r;
                Co[(size_t)m * N + o] = acc[mt][nt][r];
            }
        }
}

// ---------------- Flash attention (round-4 v4) + co-XCD head grid ------------------
// ONLY delta vs round-4: grid is (96 bh, 8 qt) so the 8 blocks sharing one head's
// K/V are contiguous in dispatch order -> same XCD -> K/V served from its L2.
__global__ __launch_bounds__(256) void attn_kernel(const u16* __restrict__ qkv,
                                                   u16* __restrict__ attn) {
    __shared__ u16 Ks[64 * 64];   // rows: key pos, cols: d  (rotated 16B chunks)
    __shared__ u16 Vs[64 * 64];   // rows: d, cols: key pos  (rotated 16B chunks)

    const int tid = threadIdx.x;
    const int w = tid >> 6, lane = tid & 63, quad = lane >> 4, l16 = lane & 15;
    const int bh = blockIdx.x, qt = blockIdx.y;
    const size_t headoff = (size_t)bh * NSEQ * DH;
    const u16* Qp = qkv + headoff;
    const u16* Kp = qkv + QKV_PART + headoff;
    const u16* Vtp = qkv + 2 * QKV_PART + headoff;
    const int q0 = qt * 128 + w * 32;

    const int rl8 = lane >> 3, cc8 = lane & 7;
    const u16* kg[2]; const u16* vg[2]; u16* kl[2]; u16* vl[2];
#pragma unroll
    for (int j = 0; j < 2; j++) {
        int r = w * 16 + j * 8 + rl8;
        int c = ((cc8 - r) & 7) * 8;
        kg[j] = Kp + (size_t)r * DH + c;
        vg[j] = Vtp + (size_t)r * NSEQ + c;
        kl[j] = Ks + (w * 16 + j * 8) * 64;
        vl[j] = Vs + (w * 16 + j * 8) * 64;
    }

    const int sw0 = ((quad + l16) & 7) * 8;
    const int sw1 = ((quad + 4 + l16) & 7) * 8;

    short8 qf[2][2];
#pragma unroll
    for (int mf = 0; mf < 2; mf++) {
        qf[mf][0] = *(const short8*)(Qp + (size_t)(q0 + mf * 16 + l16) * DH + quad * 8);
        qf[mf][1] = *(const short8*)(Qp + (size_t)(q0 + mf * 16 + l16) * DH + 32 + quad * 8);
    }

    f32x4 oacc[2][4] = {};          // O^T[d][q]
    float lsum[2] = {0.f, 0.f};

    for (int kt = 0; kt < NSEQ; kt += 64) {
        __syncthreads();
#pragma unroll
        for (int j = 0; j < 2; j++) {
            async16(kl[j], kg[j] + (size_t)kt * DH);
            async16(vl[j], vg[j] + kt);
        }
        __syncthreads();

        short8 kf[4][2];
#pragma unroll
        for (int nt = 0; nt < 4; nt++) {
            const u16* kr = Ks + (nt * 16 + l16) * 64;
            kf[nt][0] = *(const short8*)(kr + sw0);
            kf[nt][1] = *(const short8*)(kr + sw1);
        }
        short4v vf[4][4];
#pragma unroll
        for (int nt2 = 0; nt2 < 4; nt2++) {
            int row = nt2 * 16 + l16;
#pragma unroll
            for (int c = 0; c < 4; c++) {
                int off = row * 64 + (((c * 2 + (quad >> 1) + row) & 7) << 3) + (quad & 1) * 4;
                vf[nt2][c] = *(const short4v*)(Vs + off);
            }
        }

#pragma unroll
        for (int mf = 0; mf < 2; mf++) {
            f32x4 st[4];
#pragma unroll
            for (int nt = 0; nt < 4; nt++) {
                f32x4 z = {};
                z = __builtin_amdgcn_mfma_f32_16x16x32_bf16(kf[nt][0], qf[mf][0], z, 0, 0, 0);
                z = __builtin_amdgcn_mfma_f32_16x16x32_bf16(kf[nt][1], qf[mf][1], z, 0, 0, 0);
                st[nt] = z;
            }
            short4v pf[4];
#pragma unroll
            for (int c = 0; c < 4; c++) {
                float p0 = __builtin_amdgcn_exp2f(st[c][0]);
                float p1 = __builtin_amdgcn_exp2f(st[c][1]);
                float p2 = __builtin_amdgcn_exp2f(st[c][2]);
                float p3 = __builtin_amdgcn_exp2f(st[c][3]);
                lsum[mf] += (p0 + p1) + (p2 + p3);
                uint2 u = {pkbf(p0, p1), pkbf(p2, p3)};
                pf[c] = __builtin_bit_cast(short4v, u);
            }
#pragma unroll
            for (int nt2 = 0; nt2 < 4; nt2++)
#pragma unroll
                for (int c = 0; c < 4; c++)
                    oacc[mf][nt2] = mfma16(vf[nt2][c], pf[c], oacc[mf][nt2]);
        }
    }

#pragma unroll
    for (int mf = 0; mf < 2; mf++) {
        float v = lsum[mf];
        v += __shfl_xor(v, 16);
        v += __shfl_xor(v, 32);
        lsum[mf] = 1.0f / v;
    }

    const int b = bh / NH, h = bh - (bh / NH) * NH;
#pragma unroll
    for (int mf = 0; mf < 2; mf++) {
        int q = q0 + mf * 16 + l16;
        float inv = lsum[mf];
#pragma unroll
        for (int nt2 = 0; nt2 < 4; nt2++) {
            uint2 u = {pkbf(oacc[mf][nt2][0] * inv, oacc[mf][nt2][1] * inv),
                       pkbf(oacc[mf][nt2][2] * inv, oacc[mf][nt2][3] * inv)};
            int d = nt2 * 16 + quad * 4;
            *(uint2*)(attn + ((size_t)(b * NSEQ + q)) * INNER + h * DH + d) = u;
        }
    }
}

extern "C" void kernel_launch(void* const* d_in, const int* in_sizes, int n_in,
                              void* d_out, int out_size, void* d_ws, size_t ws_size,
                              hipStream_t stream) {
    const float* x = (const float*)d_in[0];
    const float* w_qkv = (const float*)d_in[1];
    const float* w_proj = (const float*)d_in[2];
    float* out = (float*)d_out;

    u16* xb = (u16*)d_ws;
    u16* wqkvb = xb + 6291456;
    u16* wprojb = wqkvb + 1769472;
    u16* qkvb = wprojb + 589824;
    u16* attnb = qkvb + 18874368;

    cvt_all<<<NCVT / 256, 256, 0, stream>>>(x, w_qkv, w_proj, xb, wqkvb, wprojb);

    dim3 g1(QKVN / 256, MTOT / 128);   // (9, 64), 512 threads
    gemm_qkv<<<g1, 512, 0, stream>>>(xb, wqkvb, qkvb);

    dim3 g2(HEADS_TOT, NSEQ / 128);    // (96, 8) — same-head blocks co-XCD
    attn_kernel<<<g2, 256, 0, stream>>>(qkvb, attnb);

    dim3 g3(INNER / 128, MTOT / 128);  // (6, 64)
    gemm_proj<<<g3, 256, 0, stream>>>(attnb, wprojb, out);
}

// Round 9
// 198.506 us; speedup vs baseline: 1.8409x; 1.0230x over previous
//
#include <hip/hip_runtime.h>
#include <stdint.h>

typedef unsigned short u16;
typedef __attribute__((ext_vector_type(8))) short short8;
typedef __attribute__((ext_vector_type(4))) short short4v;
typedef __attribute__((ext_vector_type(4))) float f32x4;

#define LOG2E 1.44269504088896340736f

#define Bb 8
#define NSEQ 1024
#define DIMC 768
#define NH 12
#define DH 64
#define INNER 768
#define MTOT (Bb*NSEQ)      /* 8192 */
#define QKVN (3*INNER)      /* 2304 */
#define HEADS_TOT (Bb*NH)   /* 96 */
#define QKV_PART ((size_t)Bb*NH*NSEQ*DH)

static __device__ inline u16 f2bf(float f) {
    uint32_t u = __builtin_bit_cast(uint32_t, f);
    uint32_t r = (u + 0x7fffu + ((u >> 16) & 1u)) >> 16;
    return (u16)r;
}

// pack two f32 -> bf16 pair (round-half-up) in 3 VALU ops via v_perm
static __device__ __forceinline__ uint32_t pkbf(float f0, float f1) {
    uint32_t u0 = __builtin_bit_cast(uint32_t, f0) + 0x8000u;
    uint32_t u1 = __builtin_bit_cast(uint32_t, f1) + 0x8000u;
    return __builtin_amdgcn_perm(u1, u0, 0x07060302u);
}

// 16x16x16 bf16 MFMA: B-operand k-packing matches 16x16 MFMA C-layout
#if __has_builtin(__builtin_amdgcn_mfma_f32_16x16x16bf16_1k)
static __device__ __forceinline__ f32x4 mfma16(short4v a, short4v b, f32x4 c) {
    return __builtin_amdgcn_mfma_f32_16x16x16bf16_1k(a, b, c, 0, 0, 0);
}
#else
static __device__ __forceinline__ f32x4 mfma16(short4v a, short4v b, f32x4 c) {
    asm volatile("v_mfma_f32_16x16x16_bf16 %0, %1, %2, %0\n\ts_nop 7\n\ts_nop 7"
                 : "+v"(c) : "v"(a), "v"(b));
    return c;
}
#endif

// ---- async global->LDS, 16B per lane; keeps staged data OUT of the VGPR file
// (round-7 VGPR staging spilled: WRITE_SIZE 42->266 MB. Do not regress this.) ----
typedef __attribute__((address_space(1))) const void gas_void;
typedef __attribute__((address_space(3))) void las_void;
static __device__ __forceinline__ void async16(u16* lds, const u16* g) {
    __builtin_amdgcn_global_load_lds((gas_void*)(uintptr_t)g,
                                     (las_void*)(uintptr_t)lds, 16, 0, 0);
}

// explicit per-wave drain of ALL outstanding vector-memory ops (vmcnt(0) only):
// simm16 = vmcnt[3:0]=0 | expcnt=7 (no wait) | lgkmcnt=0xF (no wait) = 0x0F70
static __device__ __forceinline__ void wait_vm0() {
    __builtin_amdgcn_s_waitcnt(0x0f70);
}

// ---------------- fused fp32 -> bf16 conversion (single dispatch) ----------------
#define NX8  786432
#define NWQ8 221184
#define NWP8 73728
#define NCVT (NX8 + NWQ8 + NWP8)
__global__ __launch_bounds__(256) void cvt_all(const float* __restrict__ x,
                                               const float* __restrict__ wq,
                                               const float* __restrict__ wp,
                                               u16* __restrict__ xb,
                                               u16* __restrict__ wqb,
                                               u16* __restrict__ wpb) {
    int i = blockIdx.x * 256 + threadIdx.x;
    const float* s; u16* d; int j;
    if (i < NX8) { s = x; d = xb; j = i; }
    else if (i < NX8 + NWQ8) { s = wq; d = wqb; j = i - NX8; }
    else { s = wp; d = wpb; j = i - NX8 - NWQ8; }
    const float4* s4 = (const float4*)s;
    float4 a = s4[2 * j], b = s4[2 * j + 1];
    float v[8] = {a.x, a.y, a.z, a.w, b.x, b.y, b.z, b.w};
    u16 o[8];
#pragma unroll
    for (int t = 0; t < 8; t++) o[t] = f2bf(v[t]);
    ((uint4*)d)[j] = *(const uint4*)o;
}

// ---------------- QKV GEMM: 512 thr, 128x256, BK=32, EXPLICIT-WAIT DBUF ------------
// Ping-pong LDS; ONE barrier per iter preceded by an explicit per-wave vmcnt(0).
// RAW: tile-i loads drained by wait_vm0+barrier before tile-i reads.
// WAR: each wave's ds_reads are consumed by its MFMAs before it reaches the
//      barrier; tile-(i+1) loads are issued only after passing it.
#define BK 32
__global__ __launch_bounds__(512, 4) void gemm_qkv(const u16* __restrict__ A,
                                                   const u16* __restrict__ Bm,
                                                   u16* __restrict__ qkv) {
    __shared__ u16 As[2][128 * BK];   // 2 x 8 KB
    __shared__ u16 Bs[2][256 * BK];   // 2 x 16 KB
    const int tid = threadIdx.x;
    const int w = tid >> 6, lane = tid & 63, quad = lane >> 4, l16 = lane & 15;
    const int wr = w >> 2, wc = w & 3;           // 2 x 4 wave grid, 64x64 each
    const int m0 = blockIdx.y * 128;
    const int n0 = blockIdx.x * 256;
    const int K = DIMC;

    const int rl = lane >> 2, cc = lane & 3;
    const int ra = w * 16 + rl;
    const u16* agp = A + (size_t)(m0 + ra) * K + ((cc - ((ra >> 1) & 3)) & 3) * 8;
    const int aslot = (w * 16) * BK;
    const u16* bgp[2]; int bslot[2];
#pragma unroll
    for (int j = 0; j < 2; j++) {
        int rb = w * 32 + j * 16 + rl;
        bgp[j] = Bm + (size_t)(n0 + rb) * K + ((cc - ((rb >> 1) & 3)) & 3) * 8;
        bslot[j] = (w * 32 + j * 16) * BK;
    }

    const int swz = ((quad + ((l16 >> 1) & 3)) & 3) * 8;
    int aoff[4], boff[4];
#pragma unroll
    for (int t = 0; t < 4; t++) {
        aoff[t] = (wr * 64 + t * 16 + l16) * BK + swz;
        boff[t] = (wc * 64 + t * 16 + l16) * BK + swz;
    }

    // prefetch tile 0 into buffer 0
    async16(&As[0][aslot], agp);
    async16(&Bs[0][bslot[0]], bgp[0]);
    async16(&Bs[0][bslot[1]], bgp[1]);

    f32x4 acc[4][4] = {};
    const int NIT = K / BK;   // 24
    for (int it = 0; it < NIT; ++it) {
        const int cur = it & 1, nxt = cur ^ 1;
        wait_vm0();        // my outstanding global_load_lds have landed in LDS
        __syncthreads();   // everyone's landed; prev iter's reads all consumed
        if (it + 1 < NIT) {   // prefetch tile it+1 into the other buffer
            int ktn = (it + 1) * BK;
            async16(&As[nxt][aslot], agp + ktn);
            async16(&Bs[nxt][bslot[0]], bgp[0] + ktn);
            async16(&Bs[nxt][bslot[1]], bgp[1] + ktn);
        }
        short8 af[4], bf[4];
#pragma unroll
        for (int t = 0; t < 4; t++) af[t] = *(const short8*)(&As[cur][aoff[t]]);
#pragma unroll
        for (int t = 0; t < 4; t++) bf[t] = *(const short8*)(&Bs[cur][boff[t]]);
#pragma unroll
        for (int mt = 0; mt < 4; mt++)
#pragma unroll
            for (int nt = 0; nt < 4; nt++)
                acc[mt][nt] = __builtin_amdgcn_mfma_f32_16x16x32_bf16(af[mt], bf[nt],
                                                                      acc[mt][nt], 0, 0, 0);
    }

#pragma unroll
    for (int nt = 0; nt < 4; nt++) {
        int o = n0 + wc * 64 + nt * 16 + l16;
        int which = o / 768;
        int rem = o - which * 768;
        int h = rem >> 6, d = rem & 63;
        if (which == 2) {
            u16* vt = qkv + 2 * QKV_PART;
#pragma unroll
            for (int mt = 0; mt < 4; mt++) {
                int m = m0 + wr * 64 + mt * 16 + quad * 4;
                int bb = m >> 10, ns = m & 1023;
                alignas(8) u16 pk[4];
#pragma unroll
                for (int r = 0; r < 4; r++) pk[r] = f2bf(acc[mt][nt][r]);
                *(uint2*)(vt + ((size_t)(bb * NH + h) * DH + d) * NSEQ + ns) =
                    *(const uint2*)pk;
            }
        } else {
            float sc = (which == 0) ? (0.125f * LOG2E) : 1.0f;
#pragma unroll
            for (int mt = 0; mt < 4; mt++)
#pragma unroll
                for (int r = 0; r < 4; r++) {
                    int m = m0 + wr * 64 + mt * 16 + quad * 4 + r;
                    int bb = m >> 10, ns = m & 1023;
                    size_t idx = (size_t)which * QKV_PART +
                                 (((size_t)(bb * NH + h) * NSEQ + ns) << 6) + d;
                    qkv[idx] = f2bf(acc[mt][nt][r] * sc);
                }
        }
    }
}

// ---------------- proj GEMM: 256 thr, 128x128, BK=32 (round-8 unchanged) -----------
__global__ __launch_bounds__(256) void gemm_proj(const u16* __restrict__ A,
                                                 const u16* __restrict__ Bm,
                                                 float* __restrict__ Co) {
    __shared__ u16 As[128 * BK];
    __shared__ u16 Bs[128 * BK];
    const int tid = threadIdx.x;
    const int w = tid >> 6, lane = tid & 63, quad = lane >> 4, l16 = lane & 15;
    const int wr = w >> 1, wc = w & 1;
    const int m0 = blockIdx.y * 128;
    const int n0 = blockIdx.x * 128;
    const int K = INNER, N = DIMC;

    const int rl = lane >> 2, cc = lane & 3;
    const u16* ag[2]; const u16* bg[2]; u16* al[2]; u16* bl[2];
#pragma unroll
    for (int j = 0; j < 2; j++) {
        int r = w * 32 + j * 16 + rl;
        int c = ((cc - ((r >> 1) & 3)) & 3) * 8;
        ag[j] = A + (size_t)(m0 + r) * K + c;
        bg[j] = Bm + (size_t)(n0 + r) * K + c;
        al[j] = As + (w * 32 + j * 16) * BK;
        bl[j] = Bs + (w * 32 + j * 16) * BK;
    }
    const int swz = ((quad + ((l16 >> 1) & 3)) & 3) * 8;
    int aoff[4], boff[4];
#pragma unroll
    for (int t = 0; t < 4; t++) {
        aoff[t] = (wr * 64 + t * 16 + l16) * BK + swz;
        boff[t] = (wc * 64 + t * 16 + l16) * BK + swz;
    }

    f32x4 acc[4][4] = {};
    for (int kt = 0; kt < K; kt += BK) {
        __syncthreads();
#pragma unroll
        for (int j = 0; j < 2; j++) {
            async16(al[j], ag[j] + kt);
            async16(bl[j], bg[j] + kt);
        }
        __syncthreads();
        short8 af[4], bf[4];
#pragma unroll
        for (int t = 0; t < 4; t++) af[t] = *(const short8*)(As + aoff[t]);
#pragma unroll
        for (int t = 0; t < 4; t++) bf[t] = *(const short8*)(Bs + boff[t]);
#pragma unroll
        for (int mt = 0; mt < 4; mt++)
#pragma unroll
            for (int nt = 0; nt < 4; nt++)
                acc[mt][nt] = __builtin_amdgcn_mfma_f32_16x16x32_bf16(af[mt], bf[nt],
                                                                      acc[mt][nt], 0, 0, 0);
    }
#pragma unroll
    for (int mt = 0; mt < 4; mt++)
#pragma unroll
        for (int nt = 0; nt < 4; nt++) {
            int o = n0 + wc * 64 + nt * 16 + l16;
#pragma unroll
            for (int r = 0; r < 4; r++) {
                int m = m0 + wr * 64 + mt * 16 + quad * 4 + r;
                Co[(size_t)m * N + o] = acc[mt][nt][r];
            }
        }
}

// ---------------- Flash attention (round-8 unchanged) ------------------------------
__global__ __launch_bounds__(256) void attn_kernel(const u16* __restrict__ qkv,
                                                   u16* __restrict__ attn) {
    __shared__ u16 Ks[64 * 64];   // rows: key pos, cols: d  (rotated 16B chunks)
    __shared__ u16 Vs[64 * 64];   // rows: d, cols: key pos  (rotated 16B chunks)

    const int tid = threadIdx.x;
    const int w = tid >> 6, lane = tid & 63, quad = lane >> 4, l16 = lane & 15;
    const int bh = blockIdx.x, qt = blockIdx.y;
    const size_t headoff = (size_t)bh * NSEQ * DH;
    const u16* Qp = qkv + headoff;
    const u16* Kp = qkv + QKV_PART + headoff;
    const u16* Vtp = qkv + 2 * QKV_PART + headoff;
    const int q0 = qt * 128 + w * 32;

    const int rl8 = lane >> 3, cc8 = lane & 7;
    const u16* kg[2]; const u16* vg[2]; u16* kl[2]; u16* vl[2];
#pragma unroll
    for (int j = 0; j < 2; j++) {
        int r = w * 16 + j * 8 + rl8;
        int c = ((cc8 - r) & 7) * 8;
        kg[j] = Kp + (size_t)r * DH + c;
        vg[j] = Vtp + (size_t)r * NSEQ + c;
        kl[j] = Ks + (w * 16 + j * 8) * 64;
        vl[j] = Vs + (w * 16 + j * 8) * 64;
    }

    const int sw0 = ((quad + l16) & 7) * 8;
    const int sw1 = ((quad + 4 + l16) & 7) * 8;

    short8 qf[2][2];
#pragma unroll
    for (int mf = 0; mf < 2; mf++) {
        qf[mf][0] = *(const short8*)(Qp + (size_t)(q0 + mf * 16 + l16) * DH + quad * 8);
        qf[mf][1] = *(const short8*)(Qp + (size_t)(q0 + mf * 16 + l16) * DH + 32 + quad * 8);
    }

    f32x4 oacc[2][4] = {};          // O^T[d][q]
    float lsum[2] = {0.f, 0.f};

    for (int kt = 0; kt < NSEQ; kt += 64) {
        __syncthreads();
#pragma unroll
        for (int j = 0; j < 2; j++) {
            async16(kl[j], kg[j] + (size_t)kt * DH);
            async16(vl[j], vg[j] + kt);
        }
        __syncthreads();

        short8 kf[4][2];
#pragma unroll
        for (int nt = 0; nt < 4; nt++) {
            const u16* kr = Ks + (nt * 16 + l16) * 64;
            kf[nt][0] = *(const short8*)(kr + sw0);
            kf[nt][1] = *(const short8*)(kr + sw1);
        }
        short4v vf[4][4];
#pragma unroll
        for (int nt2 = 0; nt2 < 4; nt2++) {
            int row = nt2 * 16 + l16;
#pragma unroll
            for (int c = 0; c < 4; c++) {
                int off = row * 64 + (((c * 2 + (quad >> 1) + row) & 7) << 3) + (quad & 1) * 4;
                vf[nt2][c] = *(const short4v*)(Vs + off);
            }
        }

#pragma unroll
        for (int mf = 0; mf < 2; mf++) {
            f32x4 st[4];
#pragma unroll
            for (int nt = 0; nt < 4; nt++) {
                f32x4 z = {};
                z = __builtin_amdgcn_mfma_f32_16x16x32_bf16(kf[nt][0], qf[mf][0], z, 0, 0, 0);
                z = __builtin_amdgcn_mfma_f32_16x16x32_bf16(kf[nt][1], qf[mf][1], z, 0, 0, 0);
                st[nt] = z;
            }
            short4v pf[4];
#pragma unroll
            for (int c = 0; c < 4; c++) {
                float p0 = __builtin_amdgcn_exp2f(st[c][0]);
                float p1 = __builtin_amdgcn_exp2f(st[c][1]);
                float p2 = __builtin_amdgcn_exp2f(st[c][2]);
                float p3 = __builtin_amdgcn_exp2f(st[c][3]);
                lsum[mf] += (p0 + p1) + (p2 + p3);
                uint2 u = {pkbf(p0, p1), pkbf(p2, p3)};
                pf[c] = __builtin_bit_cast(short4v, u);
            }
#pragma unroll
            for (int nt2 = 0; nt2 < 4; nt2++)
#pragma unroll
                for (int c = 0; c < 4; c++)
                    oacc[mf][nt2] = mfma16(vf[nt2][c], pf[c], oacc[mf][nt2]);
        }
    }

#pragma unroll
    for (int mf = 0; mf < 2; mf++) {
        float v = lsum[mf];
        v += __shfl_xor(v, 16);
        v += __shfl_xor(v, 32);
        lsum[mf] = 1.0f / v;
    }

    const int b = bh / NH, h = bh - (bh / NH) * NH;
#pragma unroll
    for (int mf = 0; mf < 2; mf++) {
        int q = q0 + mf * 16 + l16;
        float inv = lsum[mf];
#pragma unroll
        for (int nt2 = 0; nt2 < 4; nt2++) {
            uint2 u = {pkbf(oacc[mf][nt2][0] * inv, oacc[mf][nt2][1] * inv),
                       pkbf(oacc[mf][nt2][2] * inv, oacc[mf][nt2][3] * inv)};
            int d = nt2 * 16 + quad * 4;
            *(uint2*)(attn + ((size_t)(b * NSEQ + q)) * INNER + h * DH + d) = u;
        }
    }
}

extern "C" void kernel_launch(void* const* d_in, const int* in_sizes, int n_in,
                              void* d_out, int out_size, void* d_ws, size_t ws_size,
                              hipStream_t stream) {
    const float* x = (const float*)d_in[0];
    const float* w_qkv = (const float*)d_in[1];
    const float* w_proj = (const float*)d_in[2];
    float* out = (float*)d_out;

    u16* xb = (u16*)d_ws;
    u16* wqkvb = xb + 6291456;
    u16* wprojb = wqkvb + 1769472;
    u16* qkvb = wprojb + 589824;
    u16* attnb = qkvb + 18874368;

    cvt_all<<<NCVT / 256, 256, 0, stream>>>(x, w_qkv, w_proj, xb, wqkvb, wprojb);

    dim3 g1(QKVN / 256, MTOT / 128);   // (9, 64), 512 threads
    gemm_qkv<<<g1, 512, 0, stream>>>(xb, wqkvb, qkvb);

    dim3 g2(HEADS_TOT, NSEQ / 128);    // (96, 8) — same-head blocks co-XCD
    attn_kernel<<<g2, 256, 0, stream>>>(qkvb, attnb);

    dim3 g3(INNER / 128, MTOT / 128);  // (6, 64)
    gemm_proj<<<g3, 256, 0, stream>>>(attnb, wprojb, out);
}

// Round 10
// 187.276 us; speedup vs baseline: 1.9513x; 1.0600x over previous
//
#include <hip/hip_runtime.h>
#include <stdint.h>

typedef unsigned short u16;
typedef __attribute__((ext_vector_type(8))) short short8;
typedef __attribute__((ext_vector_type(4))) short short4v;
typedef __attribute__((ext_vector_type(4))) float f32x4;

#define LOG2E 1.44269504088896340736f

#define Bb 8
#define NSEQ 1024
#define DIMC 768
#define NH 12
#define DH 64
#define INNER 768
#define MTOT (Bb*NSEQ)      /* 8192 */
#define QKVN (3*INNER)      /* 2304 */
#define HEADS_TOT (Bb*NH)   /* 96 */
#define QKV_PART ((size_t)Bb*NH*NSEQ*DH)

static __device__ inline u16 f2bf(float f) {
    uint32_t u = __builtin_bit_cast(uint32_t, f);
    uint32_t r = (u + 0x7fffu + ((u >> 16) & 1u)) >> 16;
    return (u16)r;
}

// pack two f32 -> bf16 pair (round-half-up) in 3 VALU ops via v_perm
static __device__ __forceinline__ uint32_t pkbf(float f0, float f1) {
    uint32_t u0 = __builtin_bit_cast(uint32_t, f0) + 0x8000u;
    uint32_t u1 = __builtin_bit_cast(uint32_t, f1) + 0x8000u;
    return __builtin_amdgcn_perm(u1, u0, 0x07060302u);
}

// 16x16x16 bf16 MFMA: B-operand k-packing matches 16x16 MFMA C-layout
#if __has_builtin(__builtin_amdgcn_mfma_f32_16x16x16bf16_1k)
static __device__ __forceinline__ f32x4 mfma16(short4v a, short4v b, f32x4 c) {
    return __builtin_amdgcn_mfma_f32_16x16x16bf16_1k(a, b, c, 0, 0, 0);
}
#else
static __device__ __forceinline__ f32x4 mfma16(short4v a, short4v b, f32x4 c) {
    asm volatile("v_mfma_f32_16x16x16_bf16 %0, %1, %2, %0\n\ts_nop 7\n\ts_nop 7"
                 : "+v"(c) : "v"(a), "v"(b));
    return c;
}
#endif

// ---- async global->LDS, 16B per lane; keeps staged data OUT of the VGPR file
// (round-7 VGPR staging spilled: WRITE_SIZE 42->266 MB. Do not regress this.) ----
typedef __attribute__((address_space(1))) const void gas_void;
typedef __attribute__((address_space(3))) void las_void;
static __device__ __forceinline__ void async16(u16* lds, const u16* g) {
    __builtin_amdgcn_global_load_lds((gas_void*)(uintptr_t)g,
                                     (las_void*)(uintptr_t)lds, 16, 0, 0);
}

// explicit per-wave drain of ALL outstanding vector-memory ops (vmcnt(0) only):
// simm16 = vmcnt[3:0]=0 | expcnt=7 (no wait) | lgkmcnt=0xF (no wait) = 0x0F70
static __device__ __forceinline__ void wait_vm0() {
    __builtin_amdgcn_s_waitcnt(0x0f70);
}

// ---------------- fused fp32 -> bf16 conversion (single dispatch) ----------------
#define NX8  786432
#define NWQ8 221184
#define NWP8 73728
#define NCVT (NX8 + NWQ8 + NWP8)
__global__ __launch_bounds__(256) void cvt_all(const float* __restrict__ x,
                                               const float* __restrict__ wq,
                                               const float* __restrict__ wp,
                                               u16* __restrict__ xb,
                                               u16* __restrict__ wqb,
                                               u16* __restrict__ wpb) {
    int i = blockIdx.x * 256 + threadIdx.x;
    const float* s; u16* d; int j;
    if (i < NX8) { s = x; d = xb; j = i; }
    else if (i < NX8 + NWQ8) { s = wq; d = wqb; j = i - NX8; }
    else { s = wp; d = wpb; j = i - NX8 - NWQ8; }
    const float4* s4 = (const float4*)s;
    float4 a = s4[2 * j], b = s4[2 * j + 1];
    float v[8] = {a.x, a.y, a.z, a.w, b.x, b.y, b.z, b.w};
    u16 o[8];
#pragma unroll
    for (int t = 0; t < 8; t++) o[t] = f2bf(v[t]);
    ((uint4*)d)[j] = *(const uint4*)o;
}

// ---------------- QKV GEMM: 512 thr, 128x256, BK=32, explicit-wait dbuf ------------
// NEW: grouped-m XCD partition — XCD x computes m-panels [8x, 8x+8) x all 9 n-blocks.
// Footprint/XCD: 1.5 MB A-slice + 3.5 MB B ~= 5 MB (vs 16 MB unpartitioned).
// Writes per XCD are CONTIGUOUS ns-ranges (full-burst, unlike round-6's strided m).
#define BK 32
__global__ __launch_bounds__(512, 4) void gemm_qkv(const u16* __restrict__ A,
                                                   const u16* __restrict__ Bm,
                                                   u16* __restrict__ qkv) {
    __shared__ u16 As[2][128 * BK];   // 2 x 8 KB
    __shared__ u16 Bs[2][256 * BK];   // 2 x 16 KB
    const int tid = threadIdx.x;
    const int w = tid >> 6, lane = tid & 63, quad = lane >> 4, l16 = lane & 15;
    const int wr = w >> 2, wc = w & 3;           // 2 x 4 wave grid, 64x64 each
    const int bid = blockIdx.x + 9 * blockIdx.y; // 0..575
    const int xcd = bid & 7, j9 = bid >> 3;      // j9 in 0..71
    const int m0 = (8 * xcd + j9 / 9) * 128;     // 8 consecutive m-panels per XCD
    const int n0 = (j9 % 9) * 256;
    const int K = DIMC;

    const int rl = lane >> 2, cc = lane & 3;
    const int ra = w * 16 + rl;
    const u16* agp = A + (size_t)(m0 + ra) * K + ((cc - ((ra >> 1) & 3)) & 3) * 8;
    const int aslot = (w * 16) * BK;
    const u16* bgp[2]; int bslot[2];
#pragma unroll
    for (int j = 0; j < 2; j++) {
        int rb = w * 32 + j * 16 + rl;
        bgp[j] = Bm + (size_t)(n0 + rb) * K + ((cc - ((rb >> 1) & 3)) & 3) * 8;
        bslot[j] = (w * 32 + j * 16) * BK;
    }

    const int swz = ((quad + ((l16 >> 1) & 3)) & 3) * 8;
    int aoff[4], boff[4];
#pragma unroll
    for (int t = 0; t < 4; t++) {
        aoff[t] = (wr * 64 + t * 16 + l16) * BK + swz;
        boff[t] = (wc * 64 + t * 16 + l16) * BK + swz;
    }

    // prefetch tile 0 into buffer 0
    async16(&As[0][aslot], agp);
    async16(&Bs[0][bslot[0]], bgp[0]);
    async16(&Bs[0][bslot[1]], bgp[1]);

    f32x4 acc[4][4] = {};
    const int NIT = K / BK;   // 24
    for (int it = 0; it < NIT; ++it) {
        const int cur = it & 1, nxt = cur ^ 1;
        wait_vm0();        // my outstanding global_load_lds have landed in LDS
        __syncthreads();   // everyone's landed; prev iter's reads all consumed
        if (it + 1 < NIT) {
            int ktn = (it + 1) * BK;
            async16(&As[nxt][aslot], agp + ktn);
            async16(&Bs[nxt][bslot[0]], bgp[0] + ktn);
            async16(&Bs[nxt][bslot[1]], bgp[1] + ktn);
        }
        short8 af[4], bf[4];
#pragma unroll
        for (int t = 0; t < 4; t++) af[t] = *(const short8*)(&As[cur][aoff[t]]);
#pragma unroll
        for (int t = 0; t < 4; t++) bf[t] = *(const short8*)(&Bs[cur][boff[t]]);
#pragma unroll
        for (int mt = 0; mt < 4; mt++)
#pragma unroll
            for (int nt = 0; nt < 4; nt++)
                acc[mt][nt] = __builtin_amdgcn_mfma_f32_16x16x32_bf16(af[mt], bf[nt],
                                                                      acc[mt][nt], 0, 0, 0);
    }

#pragma unroll
    for (int nt = 0; nt < 4; nt++) {
        int o = n0 + wc * 64 + nt * 16 + l16;
        int which = o / 768;
        int rem = o - which * 768;
        int h = rem >> 6, d = rem & 63;
        if (which == 2) {
            u16* vt = qkv + 2 * QKV_PART;
#pragma unroll
            for (int mt = 0; mt < 4; mt++) {
                int m = m0 + wr * 64 + mt * 16 + quad * 4;
                int bb = m >> 10, ns = m & 1023;
                alignas(8) u16 pk[4];
#pragma unroll
                for (int r = 0; r < 4; r++) pk[r] = f2bf(acc[mt][nt][r]);
                *(uint2*)(vt + ((size_t)(bb * NH + h) * DH + d) * NSEQ + ns) =
                    *(const uint2*)pk;
            }
        } else {
            float sc = (which == 0) ? (0.125f * LOG2E) : 1.0f;
#pragma unroll
            for (int mt = 0; mt < 4; mt++)
#pragma unroll
                for (int r = 0; r < 4; r++) {
                    int m = m0 + wr * 64 + mt * 16 + quad * 4 + r;
                    int bb = m >> 10, ns = m & 1023;
                    size_t idx = (size_t)which * QKV_PART +
                                 (((size_t)(bb * NH + h) * NSEQ + ns) << 6) + d;
                    qkv[idx] = f2bf(acc[mt][nt][r] * sc);
                }
        }
    }
}

// ---------------- proj GEMM: 256 thr, 128x128, BK=32, explicit-wait dbuf -----------
__global__ __launch_bounds__(256) void gemm_proj(const u16* __restrict__ A,
                                                 const u16* __restrict__ Bm,
                                                 float* __restrict__ Co) {
    __shared__ u16 As[2][128 * BK];
    __shared__ u16 Bs[2][128 * BK];
    const int tid = threadIdx.x;
    const int w = tid >> 6, lane = tid & 63, quad = lane >> 4, l16 = lane & 15;
    const int wr = w >> 1, wc = w & 1;
    const int m0 = blockIdx.y * 128;
    const int n0 = blockIdx.x * 128;
    const int K = INNER, N = DIMC;

    const int rl = lane >> 2, cc = lane & 3;
    const u16* ag[2]; const u16* bg[2]; int sl[2];
#pragma unroll
    for (int j = 0; j < 2; j++) {
        int r = w * 32 + j * 16 + rl;
        int c = ((cc - ((r >> 1) & 3)) & 3) * 8;
        ag[j] = A + (size_t)(m0 + r) * K + c;
        bg[j] = Bm + (size_t)(n0 + r) * K + c;
        sl[j] = (w * 32 + j * 16) * BK;
    }
    const int swz = ((quad + ((l16 >> 1) & 3)) & 3) * 8;
    int aoff[4], boff[4];
#pragma unroll
    for (int t = 0; t < 4; t++) {
        aoff[t] = (wr * 64 + t * 16 + l16) * BK + swz;
        boff[t] = (wc * 64 + t * 16 + l16) * BK + swz;
    }

    // prefetch tile 0
#pragma unroll
    for (int j = 0; j < 2; j++) {
        async16(&As[0][sl[j]], ag[j]);
        async16(&Bs[0][sl[j]], bg[j]);
    }

    f32x4 acc[4][4] = {};
    const int NIT = K / BK;   // 24
    for (int it = 0; it < NIT; ++it) {
        const int cur = it & 1, nxt = cur ^ 1;
        wait_vm0();
        __syncthreads();
        if (it + 1 < NIT) {
            int ktn = (it + 1) * BK;
#pragma unroll
            for (int j = 0; j < 2; j++) {
                async16(&As[nxt][sl[j]], ag[j] + ktn);
                async16(&Bs[nxt][sl[j]], bg[j] + ktn);
            }
        }
        short8 af[4], bf[4];
#pragma unroll
        for (int t = 0; t < 4; t++) af[t] = *(const short8*)(&As[cur][aoff[t]]);
#pragma unroll
        for (int t = 0; t < 4; t++) bf[t] = *(const short8*)(&Bs[cur][boff[t]]);
#pragma unroll
        for (int mt = 0; mt < 4; mt++)
#pragma unroll
            for (int nt = 0; nt < 4; nt++)
                acc[mt][nt] = __builtin_amdgcn_mfma_f32_16x16x32_bf16(af[mt], bf[nt],
                                                                      acc[mt][nt], 0, 0, 0);
    }
#pragma unroll
    for (int mt = 0; mt < 4; mt++)
#pragma unroll
        for (int nt = 0; nt < 4; nt++) {
            int o = n0 + wc * 64 + nt * 16 + l16;
#pragma unroll
            for (int r = 0; r < 4; r++) {
                int m = m0 + wr * 64 + mt * 16 + quad * 4 + r;
                Co[(size_t)m * N + o] = acc[mt][nt][r];
            }
        }
}

// ---------------- Flash attention: explicit-wait dbuf + co-XCD heads --------------
__global__ __launch_bounds__(256) void attn_kernel(const u16* __restrict__ qkv,
                                                   u16* __restrict__ attn) {
    __shared__ u16 Ks[2][64 * 64];   // rows: key pos, cols: d  (rotated 16B chunks)
    __shared__ u16 Vs[2][64 * 64];   // rows: d, cols: key pos  (rotated 16B chunks)

    const int tid = threadIdx.x;
    const int w = tid >> 6, lane = tid & 63, quad = lane >> 4, l16 = lane & 15;
    const int bh = blockIdx.x, qt = blockIdx.y;
    const size_t headoff = (size_t)bh * NSEQ * DH;
    const u16* Qp = qkv + headoff;
    const u16* Kp = qkv + QKV_PART + headoff;
    const u16* Vtp = qkv + 2 * QKV_PART + headoff;
    const int q0 = qt * 128 + w * 32;

    const int rl8 = lane >> 3, cc8 = lane & 7;
    const u16* kg[2]; const u16* vg[2]; int ksl[2];
#pragma unroll
    for (int j = 0; j < 2; j++) {
        int r = w * 16 + j * 8 + rl8;
        int c = ((cc8 - r) & 7) * 8;
        kg[j] = Kp + (size_t)r * DH + c;
        vg[j] = Vtp + (size_t)r * NSEQ + c;
        ksl[j] = (w * 16 + j * 8) * 64;
    }

    const int sw0 = ((quad + l16) & 7) * 8;
    const int sw1 = ((quad + 4 + l16) & 7) * 8;

    short8 qf[2][2];
#pragma unroll
    for (int mf = 0; mf < 2; mf++) {
        qf[mf][0] = *(const short8*)(Qp + (size_t)(q0 + mf * 16 + l16) * DH + quad * 8);
        qf[mf][1] = *(const short8*)(Qp + (size_t)(q0 + mf * 16 + l16) * DH + 32 + quad * 8);
    }

    // prefetch tile 0 into buffer 0
#pragma unroll
    for (int j = 0; j < 2; j++) {
        async16(&Ks[0][ksl[j]], kg[j]);
        async16(&Vs[0][ksl[j]], vg[j]);
    }

    f32x4 oacc[2][4] = {};          // O^T[d][q]
    float lsum[2] = {0.f, 0.f};

    const int NIT = NSEQ / 64;   // 16
    for (int it = 0; it < NIT; ++it) {
        const int cur = it & 1, nxt = cur ^ 1;
        wait_vm0();        // my tile-it loads (and, at it=0, Q loads) have landed
        __syncthreads();
        if (it + 1 < NIT) {
            int ktn = (it + 1) * 64;
#pragma unroll
            for (int j = 0; j < 2; j++) {
                async16(&Ks[nxt][ksl[j]], kg[j] + (size_t)ktn * DH);
                async16(&Vs[nxt][ksl[j]], vg[j] + ktn);
            }
        }

        short8 kf[4][2];
#pragma unroll
        for (int nt = 0; nt < 4; nt++) {
            const u16* kr = &Ks[cur][(nt * 16 + l16) * 64];
            kf[nt][0] = *(const short8*)(kr + sw0);
            kf[nt][1] = *(const short8*)(kr + sw1);
        }
        short4v vf[4][4];
#pragma unroll
        for (int nt2 = 0; nt2 < 4; nt2++) {
            int row = nt2 * 16 + l16;
#pragma unroll
            for (int c = 0; c < 4; c++) {
                int off = row * 64 + (((c * 2 + (quad >> 1) + row) & 7) << 3) + (quad & 1) * 4;
                vf[nt2][c] = *(const short4v*)(&Vs[cur][off]);
            }
        }

#pragma unroll
        for (int mf = 0; mf < 2; mf++) {
            f32x4 st[4];
#pragma unroll
            for (int nt = 0; nt < 4; nt++) {
                f32x4 z = {};
                z = __builtin_amdgcn_mfma_f32_16x16x32_bf16(kf[nt][0], qf[mf][0], z, 0, 0, 0);
                z = __builtin_amdgcn_mfma_f32_16x16x32_bf16(kf[nt][1], qf[mf][1], z, 0, 0, 0);
                st[nt] = z;
            }
            short4v pf[4];
#pragma unroll
            for (int c = 0; c < 4; c++) {
                float p0 = __builtin_amdgcn_exp2f(st[c][0]);
                float p1 = __builtin_amdgcn_exp2f(st[c][1]);
                float p2 = __builtin_amdgcn_exp2f(st[c][2]);
                float p3 = __builtin_amdgcn_exp2f(st[c][3]);
                lsum[mf] += (p0 + p1) + (p2 + p3);
                uint2 u = {pkbf(p0, p1), pkbf(p2, p3)};
                pf[c] = __builtin_bit_cast(short4v, u);
            }
#pragma unroll
            for (int nt2 = 0; nt2 < 4; nt2++)
#pragma unroll
                for (int c = 0; c < 4; c++)
                    oacc[mf][nt2] = mfma16(vf[nt2][c], pf[c], oacc[mf][nt2]);
        }
    }

#pragma unroll
    for (int mf = 0; mf < 2; mf++) {
        float v = lsum[mf];
        v += __shfl_xor(v, 16);
        v += __shfl_xor(v, 32);
        lsum[mf] = 1.0f / v;
    }

    const int b = bh / NH, h = bh - (bh / NH) * NH;
#pragma unroll
    for (int mf = 0; mf < 2; mf++) {
        int q = q0 + mf * 16 + l16;
        float inv = lsum[mf];
#pragma unroll
        for (int nt2 = 0; nt2 < 4; nt2++) {
            uint2 u = {pkbf(oacc[mf][nt2][0] * inv, oacc[mf][nt2][1] * inv),
                       pkbf(oacc[mf][nt2][2] * inv, oacc[mf][nt2][3] * inv)};
            int d = nt2 * 16 + quad * 4;
            *(uint2*)(attn + ((size_t)(b * NSEQ + q)) * INNER + h * DH + d) = u;
        }
    }
}

extern "C" void kernel_launch(void* const* d_in, const int* in_sizes, int n_in,
                              void* d_out, int out_size, void* d_ws, size_t ws_size,
                              hipStream_t stream) {
    const float* x = (const float*)d_in[0];
    const float* w_qkv = (const float*)d_in[1];
    const float* w_proj = (const float*)d_in[2];
    float* out = (float*)d_out;

    u16* xb = (u16*)d_ws;
    u16* wqkvb = xb + 6291456;
    u16* wprojb = wqkvb + 1769472;
    u16* qkvb = wprojb + 589824;
    u16* attnb = qkvb + 18874368;

    cvt_all<<<NCVT / 256, 256, 0, stream>>>(x, w_qkv, w_proj, xb, wqkvb, wprojb);

    dim3 g1(QKVN / 256, MTOT / 128);   // (9, 64), 512 threads
    gemm_qkv<<<g1, 512, 0, stream>>>(xb, wqkvb, qkvb);

    dim3 g2(HEADS_TOT, NSEQ / 128);    // (96, 8) — same-head blocks co-XCD
    attn_kernel<<<g2, 256, 0, stream>>>(qkvb, attnb);

    dim3 g3(INNER / 128, MTOT / 128);  // (6, 64)
    gemm_proj<<<g3, 256, 0, stream>>>(attnb, wprojb, out);
}